// Round 15
// baseline (331.562 us; speedup 1.0000x reference)
//
#include <hip/hip_runtime.h>
#include <stdint.h>

#define B_ 32
#define T_ 4096
#define D_ 512
#define BT_ (B_*T_)
#define NTILE_ 2048        // 64-row tiles
#define GRID_ 256          // persistent blocks (1/CU)

typedef __attribute__((ext_vector_type(8))) short bf16x8;
typedef __attribute__((ext_vector_type(4))) float f32x4;

__device__ __forceinline__ unsigned short f2bf(float f) {
    unsigned int u = __float_as_uint(f);
    u += 0x7FFFu + ((u >> 16) & 1u);   // round-to-nearest-even (inputs are finite)
    return (unsigned short)(u >> 16);
}

__device__ __forceinline__ unsigned pk2(float a, float b) {
    return (unsigned)f2bf(a) | ((unsigned)f2bf(b) << 16);   // low16 = a, high16 = b
}

__device__ __forceinline__ float tanh_fast(float x) {
    float e2 = __expf(2.0f * x);
    return 1.0f - 2.0f / (e2 + 1.0f);
}

// ---------------------------------------------------------------------------
// W_h (D x D fp32, [k][n]) -> bf16 MFMA B-fragment layout in ws (unchanged).
__global__ __launch_bounds__(256) void k_conv_wh(const float* __restrict__ W_h,
                                                 unsigned short* __restrict__ wsb) {
    int tid = blockIdx.x * 256 + threadIdx.x;
    int l  = tid & 63;
    int kt = (tid >> 6) & 15;
    int nt = tid >> 10;
    int n  = nt * 16 + (l & 15);
    int k0 = kt * 32 + (l >> 4) * 8;
    unsigned int w[4];
#pragma unroll
    for (int q = 0; q < 4; ++q) {
        unsigned short lo = f2bf(W_h[(size_t)(k0 + 2*q)     * D_ + n]);
        unsigned short hi = f2bf(W_h[(size_t)(k0 + 2*q + 1) * D_ + n]);
        w[q] = (unsigned int)lo | ((unsigned int)hi << 16);
    }
    uint4 pk = {w[0], w[1], w[2], w[3]};
    ((uint4*)wsb)[tid] = pk;
}

// ---------------------------------------------------------------------------
__global__ __launch_bounds__(256) void k_dec(const float* __restrict__ s_t,
                                             const float* __restrict__ W_s,
                                             const float* __restrict__ b_s,
                                             float* __restrict__ dec) {
    int b = blockIdx.x;
    int c = threadIdx.x;
    float a0 = b_s[c], a1 = b_s[c + 256];
    const float* srow = s_t + b * D_;
    for (int k = 0; k < D_; ++k) {
        float s = srow[k];
        const float* wr = W_s + (size_t)k * D_;
        a0 = fmaf(s, wr[c], a0);
        a1 = fmaf(s, wr[c + 256], a1);
    }
    dec[b * D_ + c] = a0;
    dec[b * D_ + c + 256] = a1;
}

// ---------------------------------------------------------------------------
// Persistent main kernel. 256 blocks x 1024 thr (16 waves), launch_bounds
// (1024,4) -> 128-reg budget (acc 32 AGPR + ~50 VGPR, margin vs R10/R12).
// Each block processes 8 tiles of 64 rows (tile = bid + 256*t), double-
// buffered bf16 panels (2 x 64KB, sigma-swizzled frag layout, R12-proven):
// while the K-loop computes tile t from bufc, it stages tile t+1 into bufn
// in 4 chunks -- chunk g: issue loads, 4 kt of MFMA (~620cy, covers L3
// latency), convert+write. Staging latency is structurally hidden; the
// serial stage->barrier->compute cost is paid once per block, not per tile.
// Wave w computes cols [w*32, w*32+32). Epilogue: fused tanh/V-dot -> e_t;
// fused context partial from the resident panel (kt = w).
__global__ __launch_bounds__(1024, 4) void k_main(const float* __restrict__ h_i,
                                                  const float* __restrict__ coverage,
                                                  const unsigned short* __restrict__ wsb,
                                                  const float* __restrict__ dec,
                                                  const float* __restrict__ W_c,
                                                  const float* __restrict__ V,
                                                  float* __restrict__ e_out,
                                                  float* __restrict__ part) {
    __shared__ __align__(16) unsigned char As[2][65536];
    __shared__ float red[16][64];
    __shared__ float wexp[64];
    const int tid = threadIdx.x;
    const int w = tid >> 6, l = tid & 63;      // w: 0..15

    // staging-side constants (R12 algebra: pass/chunk p -> frag af=p; wave w
    // stages row w+16p; lane l covers k-chunk l (8 floats) of that row)
    const int kt_s = l >> 2;
    const int lamf = ((l & 3) << 4) + w;
    const int slot = (lamf & 0x38) | ((lamf & 7) ^ ((l & 3) << 1) ^ (kt_s & 1));
    const int sb0  = (kt_s << 10) + (slot << 4);

    // compute-side constants
    const int slotR = (l & 0x38) | ((l & 7) ^ (((l >> 4) & 3) << 1));
    const int rgrp  = (l >> 4) * 4;
    const uint4* bw = (const uint4*)wsb + ((w * 2) << 10) + l;

    // per-col constants (independent of tile)
    const int colb = w * 32 + (l & 15);
    const float wc0 = W_c[colb],      vv0 = V[colb];
    const float wc1 = W_c[colb + 16], vv1 = V[colb + 16];

    unsigned char* bufc = As[0];
    unsigned char* bufn = As[1];

    // ---- prologue: stage tile (bid) fully into bufc (once per block)
    {
        const float* g0 = h_i + (size_t)(blockIdx.x * 64 + w) * D_ + l * 8;
#pragma unroll
        for (int p = 0; p < 4; ++p) {
            float4 f0 = *(const float4*)(g0 + (size_t)(16 * p) * D_);
            float4 f1 = *(const float4*)(g0 + (size_t)(16 * p) * D_ + 4);
            uint4 pk;
            pk.x = pk2(f0.x, f0.y); pk.y = pk2(f0.z, f0.w);
            pk.z = pk2(f1.x, f1.y); pk.w = pk2(f1.z, f1.w);
            *(uint4*)(bufc + (p << 14) + sb0) = pk;
        }
    }
    __syncthreads();

#pragma unroll 1
    for (int t = 0; t < 8; ++t) {
        const int tile = blockIdx.x + t * GRID_;
        const int row0 = tile * 64;
        const int b    = row0 >> 12;
        const int t0   = row0 & (T_ - 1);
        const bool hn  = (t < 7);
        // next tile's staging source (same block, +256 tiles ahead)
        const float* gn = h_i + (size_t)(row0 + GRID_ * 64 + w) * D_ + l * 8;

        f32x4 acc[4][2];
#pragma unroll
        for (int af = 0; af < 4; ++af) {
            acc[af][0] = (f32x4){0, 0, 0, 0};
            acc[af][1] = (f32x4){0, 0, 0, 0};
        }

        // ---- K loop: 4 groups; group g stages chunk g of tile t+1
#define KGROUP(g)                                                             \
        {                                                                     \
            float4 f0, f1;                                                    \
            if (hn) {                                                         \
                f0 = *(const float4*)(gn + (size_t)(16 * (g)) * D_);          \
                f1 = *(const float4*)(gn + (size_t)(16 * (g)) * D_ + 4);      \
            }                                                                 \
            _Pragma("unroll")                                                 \
            for (int kk = 0; kk < 4; ++kk) {                                  \
                const int kt = (g) * 4 + kk;                                  \
                const int sl = (slotR ^ (kt & 1)) << 4;                       \
                uint4 b0 = bw[(kt << 6)];                                     \
                uint4 b1 = bw[(1 << 10) + (kt << 6)];                         \
                _Pragma("unroll")                                             \
                for (int af = 0; af < 4; ++af) {                              \
                    uint4 araw = *(const uint4*)(bufc + ((af * 16 + kt) << 10) + sl); \
                    bf16x8 a = __builtin_bit_cast(bf16x8, araw);              \
                    acc[af][0] = __builtin_amdgcn_mfma_f32_16x16x32_bf16(     \
                        a, __builtin_bit_cast(bf16x8, b0), acc[af][0], 0, 0, 0); \
                    acc[af][1] = __builtin_amdgcn_mfma_f32_16x16x32_bf16(     \
                        a, __builtin_bit_cast(bf16x8, b1), acc[af][1], 0, 0, 0); \
                }                                                             \
            }                                                                 \
            if (hn) {                                                         \
                uint4 pk;                                                     \
                pk.x = pk2(f0.x, f0.y); pk.y = pk2(f0.z, f0.w);               \
                pk.z = pk2(f1.x, f1.y); pk.w = pk2(f1.z, f1.w);               \
                *(uint4*)(bufn + ((g) << 14) + sb0) = pk;                     \
            }                                                                 \
        }

        KGROUP(0)
        KGROUP(1)
        KGROUP(2)
        KGROUP(3)
#undef KGROUP

        // ---- epilogue: tanh + dot with V over this wave's 32 cols
        {
            float dv0 = dec[b * D_ + colb];
            float dv1 = dec[b * D_ + colb + 16];
            float p2[4][4];
#pragma unroll
            for (int af = 0; af < 4; ++af) {
#pragma unroll
                for (int r = 0; r < 4; ++r) {
                    float cv = coverage[b * T_ + t0 + af * 16 + rgrp + r];
                    float x0 = acc[af][0][r] + dv0 + cv * wc0;
                    float x1 = acc[af][1][r] + dv1 + cv * wc1;
                    p2[af][r] = tanh_fast(x0) * vv0 + tanh_fast(x1) * vv1;
                }
            }
#pragma unroll
            for (int mm = 1; mm <= 8; mm <<= 1)
#pragma unroll
                for (int af = 0; af < 4; ++af)
#pragma unroll
                    for (int r = 0; r < 4; ++r)
                        p2[af][r] += __shfl_xor(p2[af][r], mm, 64);
            if ((l & 15) == 0) {
#pragma unroll
                for (int af = 0; af < 4; ++af)
#pragma unroll
                    for (int r = 0; r < 4; ++r)
                        red[w][af * 16 + rgrp + r] = p2[af][r];
            }
        }
        __syncthreads();                        // B1: red ready, bufn writes done
        if (tid < 64) {
            float e = 0.f;
#pragma unroll
            for (int ww = 0; ww < 16; ++ww) e += red[ww][tid];
            e_out[b * T_ + t0 + tid] = e;
            wexp[tid] = __expf(e);
        }
        __syncthreads();                        // B2: wexp ready

        // ---- fused context partial from bufc. Wave w: kt = w.
        {
            float pc[8] = {0, 0, 0, 0, 0, 0, 0, 0};
            const int sl = (slotR ^ (w & 1)) << 4;
#pragma unroll
            for (int af = 0; af < 4; ++af) {
                float wv = wexp[af * 16 + (l & 15)];
                uint4 araw = *(const uint4*)(bufc + ((af * 16 + w) << 10) + sl);
                const unsigned* u = (const unsigned*)&araw;
#pragma unroll
                for (int q = 0; q < 4; ++q) {
                    float g0 = __uint_as_float(u[q] << 16);
                    float g1 = __uint_as_float(u[q] & 0xffff0000u);
                    pc[2 * q]     = fmaf(wv, g0, pc[2 * q]);
                    pc[2 * q + 1] = fmaf(wv, g1, pc[2 * q + 1]);
                }
            }
#pragma unroll
            for (int mm = 1; mm <= 8; mm <<= 1)
#pragma unroll
                for (int j = 0; j < 8; ++j)
                    pc[j] += __shfl_xor(pc[j], mm, 64);
            if ((l & 15) == 0) {
                float* dst = part + (size_t)tile * D_ + w * 32 + (l >> 4) * 8;
                *(float4*)dst       = float4{pc[0], pc[1], pc[2], pc[3]};
                *(float4*)(dst + 4) = float4{pc[4], pc[5], pc[6], pc[7]};
            }
        }
        __syncthreads();                        // B3: bufc reads done before next
                                                //     tile's staging overwrites it
        unsigned char* tmp = bufc; bufc = bufn; bufn = tmp;
    }
}

// ---------------------------------------------------------------------------
__global__ __launch_bounds__(256) void k_soft(const float* __restrict__ e_in,
                                              const float* __restrict__ coverage,
                                              float* __restrict__ out_at,
                                              float* __restrict__ out_cov,
                                              float* __restrict__ Sb) {
    int b = blockIdx.x, tid = threadIdx.x;
    __shared__ float red[4];
    float v[16];
    float m = -1e30f;
#pragma unroll
    for (int i = 0; i < 16; ++i) {
        v[i] = e_in[b * T_ + tid + i * 256];
        m = fmaxf(m, v[i]);
    }
#pragma unroll
    for (int mk = 1; mk <= 32; mk <<= 1) m = fmaxf(m, __shfl_xor(m, mk, 64));
    if ((tid & 63) == 0) red[tid >> 6] = m;
    __syncthreads();
    m = fmaxf(fmaxf(red[0], red[1]), fmaxf(red[2], red[3]));
    float s = 0.f;
#pragma unroll
    for (int i = 0; i < 16; ++i) { v[i] = expf(v[i] - m); s += v[i]; }
#pragma unroll
    for (int mk = 1; mk <= 32; mk <<= 1) s += __shfl_xor(s, mk, 64);
    __syncthreads();
    if ((tid & 63) == 0) red[tid >> 6] = s;
    __syncthreads();
    s = red[0] + red[1] + red[2] + red[3];
    if (tid == 0) Sb[b] = __expf(m) * s;
    float inv = 1.0f / s;
#pragma unroll
    for (int i = 0; i < 16; ++i) {
        int idx = b * T_ + tid + i * 256;
        float a = v[i] * inv;
        out_at[idx]  = a;
        out_cov[idx] = coverage[idx] + a;
    }
}

// ---------------------------------------------------------------------------
// combine: context[b][d] = (sum_{s=0..63} part[(b*64+s)][d]) / S_b
__global__ __launch_bounds__(256) void k_comb(const float* __restrict__ part,
                                              const float* __restrict__ Sb,
                                              float* __restrict__ out_ctx) {
    int idx = blockIdx.x * 256 + threadIdx.x;
    int b = idx >> 9, d = idx & 511;
    const float* pp = part + (size_t)b * 64 * D_ + d;
    float s = 0.f;
#pragma unroll 8
    for (int j = 0; j < 64; ++j) s += pp[(size_t)j * D_];
    out_ctx[idx] = s / Sb[b];
}

// ---------------------------------------------------------------------------
extern "C" void kernel_launch(void* const* d_in, const int* in_sizes, int n_in,
                              void* d_out, int out_size, void* d_ws, size_t ws_size,
                              hipStream_t stream) {
    const float* h_i      = (const float*)d_in[0];
    const float* s_t      = (const float*)d_in[1];
    const float* coverage = (const float*)d_in[2];
    const float* W_h      = (const float*)d_in[3];
    const float* W_s      = (const float*)d_in[4];
    const float* b_s      = (const float*)d_in[5];
    const float* W_c      = (const float*)d_in[6];
    const float* V        = (const float*)d_in[7];

    float* out_ctx = (float*)d_out;             // B*D
    float* out_at  = out_ctx + B_ * D_;         // B*T (e_t between k_main and k_soft)
    float* out_cov = out_at + BT_;              // B*T

    unsigned short* wsb = (unsigned short*)d_ws;              // 512 KB bf16 W_h frags
    float* dec  = (float*)((char*)d_ws + 524288);             // 64 KB
    float* part = dec + B_ * D_;                              // 4 MB (2048 x 512 fp32)
    float* Sb   = part + (size_t)NTILE_ * D_;                 // 32 floats

    k_conv_wh<<<128, 256, 0, stream>>>(W_h, wsb);
    k_dec<<<B_, 256, 0, stream>>>(s_t, W_s, b_s, dec);
    k_main<<<GRID_, 1024, 0, stream>>>(h_i, coverage, wsb, dec, W_c, V, out_at, part);
    k_soft<<<B_, 256, 0, stream>>>(out_at, coverage, out_at, out_cov, Sb);
    k_comb<<<B_ * D_ / 256, 256, 0, stream>>>(part, Sb, out_ctx);
}

// Round 16
// 160.560 us; speedup vs baseline: 2.0650x; 2.0650x over previous
//
#include <hip/hip_runtime.h>
#include <stdint.h>

#define B_ 32
#define T_ 4096
#define D_ 512
#define BT_ (B_*T_)
#define ROWS_ 64          // rows per block
#define NBLK_ (BT_/ROWS_) // 2048

typedef __attribute__((ext_vector_type(8))) short bf16x8;
typedef __attribute__((ext_vector_type(4))) float f32x4;

__device__ __forceinline__ unsigned short f2bf(float f) {
    unsigned int u = __float_as_uint(f);
    u += 0x7FFFu + ((u >> 16) & 1u);   // round-to-nearest-even (inputs are finite)
    return (unsigned short)(u >> 16);
}

__device__ __forceinline__ unsigned pk2(float a, float b) {
    return (unsigned)f2bf(a) | ((unsigned)f2bf(b) << 16);   // low16 = a, high16 = b
}

__device__ __forceinline__ float bf2f(unsigned short u) {
    return __uint_as_float(((unsigned)u) << 16);
}

__device__ __forceinline__ float tanh_fast(float x) {
    float e2 = __expf(2.0f * x);
    return 1.0f - 2.0f / (e2 + 1.0f);
}

// ---------------------------------------------------------------------------
// W_h (D x D fp32, [k][n]) -> bf16 MFMA B-fragment layout in ws (unchanged).
__global__ __launch_bounds__(256) void k_conv_wh(const float* __restrict__ W_h,
                                                 unsigned short* __restrict__ wsb) {
    int tid = blockIdx.x * 256 + threadIdx.x;
    int l  = tid & 63;
    int kt = (tid >> 6) & 15;
    int nt = tid >> 10;
    int n  = nt * 16 + (l & 15);
    int k0 = kt * 32 + (l >> 4) * 8;
    unsigned int w[4];
#pragma unroll
    for (int q = 0; q < 4; ++q) {
        unsigned short lo = f2bf(W_h[(size_t)(k0 + 2*q)     * D_ + n]);
        unsigned short hi = f2bf(W_h[(size_t)(k0 + 2*q + 1) * D_ + n]);
        w[q] = (unsigned int)lo | ((unsigned int)hi << 16);
    }
    uint4 pk = {w[0], w[1], w[2], w[3]};
    ((uint4*)wsb)[tid] = pk;
}

// ---------------------------------------------------------------------------
__global__ __launch_bounds__(256) void k_dec(const float* __restrict__ s_t,
                                             const float* __restrict__ W_s,
                                             const float* __restrict__ b_s,
                                             float* __restrict__ dec) {
    int b = blockIdx.x;
    int c = threadIdx.x;
    float a0 = b_s[c], a1 = b_s[c + 256];
    const float* srow = s_t + b * D_;
    for (int k = 0; k < D_; ++k) {
        float s = srow[k];
        const float* wr = W_s + (size_t)k * D_;
        a0 = fmaf(s, wr[c], a0);
        a1 = fmaf(s, wr[c + 256], a1);
    }
    dec[b * D_ + c] = a0;
    dec[b * D_ + c + 256] = a1;
}

// ---------------------------------------------------------------------------
// Main fused kernel. Block = 64 rows of (B*T), 16 waves (1024 threads),
// launch_bounds(1024,8) -> 64-reg unified budget, 2 blocks/CU, 8 waves/SIMD.
// acc[4][2] = 32 AGPR; NO explicit prefetch arrays (spill source in R10) --
// B loads issue directly in the unrolled K-loop, TLP (8 waves/SIMD) hides L2.
// bf16 panel (64 rows x 512 K = 64KB LDS), sigma-swizzled, convert-on-write.
// Wave w computes cols [w*32, w*32+32).
__global__ __launch_bounds__(1024, 8) void k_main(const float* __restrict__ h_i,
                                                  const float* __restrict__ coverage,
                                                  const unsigned short* __restrict__ wsb,
                                                  const float* __restrict__ dec,
                                                  const float* __restrict__ W_c,
                                                  const float* __restrict__ V,
                                                  float* __restrict__ e_out,
                                                  unsigned short* __restrict__ part) {
    __shared__ __align__(16) unsigned char As[65536];   // 64 frags x 1KB
    __shared__ float red[16][ROWS_];
    __shared__ float wexp[ROWS_];
    const int tid = threadIdx.x;
    const int w = tid >> 6, l = tid & 63;      // w: 0..15
    const int row0 = blockIdx.x * ROWS_;
    const int b    = row0 >> 12;
    const int t0   = row0 & (T_ - 1);

    // ---- stage A: pass p in 0..3: wave w stages row w+16p, lane l chunk l.
    // frag f = p*16 + (l>>2); slot = sigma(lamf, kt_s), lamf = w + 16*(l&3).
    {
        const int kt_s = l >> 2;
        const int lamf = ((l & 3) << 4) + w;           // row&15 == w
        const int slot = (lamf & 0x38) | ((lamf & 7) ^ ((l & 3) << 1) ^ (kt_s & 1));
        const int sb0  = (kt_s << 10) + (slot << 4);
        const float* gsrc = h_i + (size_t)(row0 + w) * D_ + l * 8;
#pragma unroll
        for (int p = 0; p < 4; ++p) {
            const float* src = gsrc + (size_t)(16 * p) * D_;
            float4 f0 = *(const float4*)src;
            float4 f1 = *(const float4*)(src + 4);
            uint4 pk;
            pk.x = pk2(f0.x, f0.y);
            pk.y = pk2(f0.z, f0.w);
            pk.z = pk2(f1.x, f1.y);
            pk.w = pk2(f1.z, f1.w);
            *(uint4*)(As + (p << 14) + sb0) = pk;      // af = p
        }
    }
    __syncthreads();

    // ---- K loop: wave w, cols nt = w*2 + {0,1}; direct B loads (no arrays)
    const int slotR = (l & 0x38) | ((l & 7) ^ (((l >> 4) & 3) << 1));
    const uint4* bw = (const uint4*)wsb + ((w * 2) << 10) + l;

    f32x4 acc[4][2];
#pragma unroll
    for (int af = 0; af < 4; ++af) {
        acc[af][0] = (f32x4){0, 0, 0, 0};
        acc[af][1] = (f32x4){0, 0, 0, 0};
    }

#pragma unroll
    for (int kt = 0; kt < 16; ++kt) {
        const int sl = (slotR ^ (kt & 1)) << 4;
        uint4 b0 = bw[(kt << 6)];
        uint4 b1 = bw[(1 << 10) + (kt << 6)];
#pragma unroll
        for (int af = 0; af < 4; ++af) {
            uint4 araw = *(const uint4*)(As + ((af * 16 + kt) << 10) + sl);
            bf16x8 a = __builtin_bit_cast(bf16x8, araw);
            acc[af][0] = __builtin_amdgcn_mfma_f32_16x16x32_bf16(
                a, __builtin_bit_cast(bf16x8, b0), acc[af][0], 0, 0, 0);
            acc[af][1] = __builtin_amdgcn_mfma_f32_16x16x32_bf16(
                a, __builtin_bit_cast(bf16x8, b1), acc[af][1], 0, 0, 0);
        }
    }

    // ---- epilogue: tanh + dot with V over this wave's 32 cols
    const int rgrp = (l >> 4) * 4;
    float p2[4][4] = {{0,0,0,0},{0,0,0,0},{0,0,0,0},{0,0,0,0}};
    {
        int col0 = w * 32 + (l & 15);
        float dv0 = dec[b * D_ + col0],      wc0 = W_c[col0],      vv0 = V[col0];
        float dv1 = dec[b * D_ + col0 + 16], wc1 = W_c[col0 + 16], vv1 = V[col0 + 16];
#pragma unroll
        for (int af = 0; af < 4; ++af) {
            float cov_r[4];
#pragma unroll
            for (int r = 0; r < 4; ++r)
                cov_r[r] = coverage[b * T_ + t0 + af * 16 + rgrp + r];
#pragma unroll
            for (int r = 0; r < 4; ++r) {
                float x0 = acc[af][0][r] + dv0 + cov_r[r] * wc0;
                float x1 = acc[af][1][r] + dv1 + cov_r[r] * wc1;
                p2[af][r] += tanh_fast(x0) * vv0 + tanh_fast(x1) * vv1;
            }
        }
    }

    // reduce across the 16 lanes sharing each row (lane bits 0..3)
#pragma unroll
    for (int mm = 1; mm <= 8; mm <<= 1)
#pragma unroll
        for (int af = 0; af < 4; ++af)
#pragma unroll
            for (int r = 0; r < 4; ++r)
                p2[af][r] += __shfl_xor(p2[af][r], mm, 64);
    if ((l & 15) == 0) {
#pragma unroll
        for (int af = 0; af < 4; ++af)
#pragma unroll
            for (int r = 0; r < 4; ++r)
                red[w][af * 16 + rgrp + r] = p2[af][r];
    }
    __syncthreads();
    if (tid < ROWS_) {
        float e = 0.f;
#pragma unroll
        for (int ww = 0; ww < 16; ++ww) e += red[ww][tid];
        e_out[b * T_ + t0 + tid] = e;
        wexp[tid] = __expf(e);
    }
    __syncthreads();

    // ---- fused context partial (bf16) from the panel. Wave w: kt = w.
    {
        float pc[8] = {0, 0, 0, 0, 0, 0, 0, 0};
        const int sl = (slotR ^ (w & 1)) << 4;
#pragma unroll
        for (int af = 0; af < 4; ++af) {
            float wv = wexp[af * 16 + (l & 15)];
            uint4 araw = *(const uint4*)(As + ((af * 16 + w) << 10) + sl);
            const unsigned* u = (const unsigned*)&araw;
#pragma unroll
            for (int q = 0; q < 4; ++q) {
                float f0 = __uint_as_float(u[q] << 16);
                float f1 = __uint_as_float(u[q] & 0xffff0000u);
                pc[2 * q]     = fmaf(wv, f0, pc[2 * q]);
                pc[2 * q + 1] = fmaf(wv, f1, pc[2 * q + 1]);
            }
        }
#pragma unroll
        for (int mm = 1; mm <= 8; mm <<= 1)
#pragma unroll
            for (int j = 0; j < 8; ++j)
                pc[j] += __shfl_xor(pc[j], mm, 64);
        if ((l & 15) == 0) {
            unsigned short* dst = part + (size_t)blockIdx.x * D_ + w * 32 + (l >> 4) * 8;
            unsigned* d32 = (unsigned*)dst;
            d32[0] = pk2(pc[0], pc[1]);
            d32[1] = pk2(pc[2], pc[3]);
            d32[2] = pk2(pc[4], pc[5]);
            d32[3] = pk2(pc[6], pc[7]);
        }
    }
}

// ---------------------------------------------------------------------------
__global__ __launch_bounds__(256) void k_soft(const float* __restrict__ e_in,
                                              const float* __restrict__ coverage,
                                              float* __restrict__ out_at,
                                              float* __restrict__ out_cov,
                                              float* __restrict__ Sb) {
    int b = blockIdx.x, tid = threadIdx.x;
    __shared__ float red[4];
    float v[16];
    float m = -1e30f;
#pragma unroll
    for (int i = 0; i < 16; ++i) {
        v[i] = e_in[b * T_ + tid + i * 256];
        m = fmaxf(m, v[i]);
    }
#pragma unroll
    for (int mk = 1; mk <= 32; mk <<= 1) m = fmaxf(m, __shfl_xor(m, mk, 64));
    if ((tid & 63) == 0) red[tid >> 6] = m;
    __syncthreads();
    m = fmaxf(fmaxf(red[0], red[1]), fmaxf(red[2], red[3]));
    float s = 0.f;
#pragma unroll
    for (int i = 0; i < 16; ++i) { v[i] = expf(v[i] - m); s += v[i]; }
#pragma unroll
    for (int mk = 1; mk <= 32; mk <<= 1) s += __shfl_xor(s, mk, 64);
    __syncthreads();
    if ((tid & 63) == 0) red[tid >> 6] = s;
    __syncthreads();
    s = red[0] + red[1] + red[2] + red[3];
    if (tid == 0) Sb[b] = __expf(m) * s;
    float inv = 1.0f / s;
#pragma unroll
    for (int i = 0; i < 16; ++i) {
        int idx = b * T_ + tid + i * 256;
        float a = v[i] * inv;
        out_at[idx]  = a;
        out_cov[idx] = coverage[idx] + a;
    }
}

// ---------------------------------------------------------------------------
// combine: context[b][d] = (sum_s part_bf16[(b*64+s)][d]) / S_b  (deterministic)
__global__ __launch_bounds__(256) void k_comb(const unsigned short* __restrict__ part,
                                              const float* __restrict__ Sb,
                                              float* __restrict__ out_ctx) {
    int idx = blockIdx.x * 256 + threadIdx.x;
    int b = idx >> 9, d = idx & 511;
    const unsigned short* pp = part + (size_t)b * 64 * D_ + d;
    float s = 0.f;
#pragma unroll 8
    for (int j = 0; j < 64; ++j) s += bf2f(pp[(size_t)j * D_]);
    out_ctx[idx] = s / Sb[b];
}

// ---------------------------------------------------------------------------
extern "C" void kernel_launch(void* const* d_in, const int* in_sizes, int n_in,
                              void* d_out, int out_size, void* d_ws, size_t ws_size,
                              hipStream_t stream) {
    const float* h_i      = (const float*)d_in[0];
    const float* s_t      = (const float*)d_in[1];
    const float* coverage = (const float*)d_in[2];
    const float* W_h      = (const float*)d_in[3];
    const float* W_s      = (const float*)d_in[4];
    const float* b_s      = (const float*)d_in[5];
    const float* W_c      = (const float*)d_in[6];
    const float* V        = (const float*)d_in[7];

    float* out_ctx = (float*)d_out;             // B*D
    float* out_at  = out_ctx + B_ * D_;         // B*T (e_t between k_main and k_soft)
    float* out_cov = out_at + BT_;              // B*T

    unsigned short* wsb = (unsigned short*)d_ws;              // 512 KB bf16 W_h frags
    float* dec  = (float*)((char*)d_ws + 524288);             // 64 KB
    unsigned short* part = (unsigned short*)(dec + B_ * D_);  // 2 MB (2048 x 512 bf16)
    float* Sb   = (float*)(part + (size_t)NBLK_ * D_);        // 32 floats

    k_conv_wh<<<128, 256, 0, stream>>>(W_h, wsb);
    k_dec<<<B_, 256, 0, stream>>>(s_t, W_s, b_s, dec);
    k_main<<<NBLK_, 1024, 0, stream>>>(h_i, coverage, wsb, dec, W_c, V, out_at, part);
    k_soft<<<B_, 256, 0, stream>>>(out_at, coverage, out_at, out_cov, Sb);
    k_comb<<<B_ * D_ / 256, 256, 0, stream>>>(part, Sb, out_ctx);
}